// Round 1
// 8630.700 us; speedup vs baseline: 1.0230x; 1.0230x over previous
//
#include <hip/hip_runtime.h>

#define TT 800

typedef __attribute__((ext_vector_type(8))) short bf16x8;
typedef __attribute__((ext_vector_type(4))) float f32x4;
typedef unsigned short u16;
typedef unsigned int u32;
typedef unsigned long long u64;

constexpr int NCW = 128, NWG = 136, RT = 32;
constexpr size_t WL0A_OFF = 0;              // [2048][512] bf16 = 2,097,152 (W_hh0, K-major)
constexpr size_t WL0B_OFF = 2097152;        // [128][2048] bf16 = 524,288  (W_ih0^T row-gather)
constexpr size_t WL1_OFF  = 2621440;        // [2048][1024] bf16
constexpr size_t WLIN_OFF = 6815744;        // [128][512] bf16
constexpr size_t H0_OFF   = 6946816;        // [2][256][512] bf16
constexpr size_t H1_OFF   = 7471104;        // [2][256][512] bf16
constexpr size_t BAR_OFF  = 7995392;        // 8 tiles * 128B flags
constexpr int HB = 256 * 512;
// LDS: A = 32 rows x 520 u16 = 33280 B; Gf = 32 x 129 f32 = 16512 B @33280;
// P = 3 x 256 f32 = 3072 B @49792. Total 52864 (<64K, no opt-in needed).
constexpr int A_ST = 520;
constexpr int G_OFF_B = 33280;
constexpr int P_OFF_B = 49792;
constexpr int LDS_BYTES = 53248;

__device__ __forceinline__ u16 f2b(float x) {
  u32 u = __float_as_uint(x);
  return (u16)((u + 0x7FFFu + ((u >> 16) & 1u)) >> 16);   // RNE fp32->bf16
}
__device__ __forceinline__ float b2f(u16 v) { return __uint_as_float(((u32)v) << 16); }
__device__ __forceinline__ float sigf(float x) { return 1.f / (1.f + __expf(-x)); }
__device__ __forceinline__ float tanh_f(float x) { float e = __expf(2.f * x); return 1.f - 2.f / (e + 1.f); }

__device__ __forceinline__ u64 ld_coh8(const u64* p) {
  return __hip_atomic_load(p, __ATOMIC_RELAXED, __HIP_MEMORY_SCOPE_AGENT);
}
__device__ __forceinline__ void st_coh8(u64* p, u64 v) {
  __hip_atomic_store(p, v, __ATOMIC_RELAXED, __HIP_MEMORY_SCOPE_AGENT);
}
__device__ __forceinline__ void fadd(u32* f) {
  __hip_atomic_fetch_add(f, 1u, __ATOMIC_RELAXED, __HIP_MEMORY_SCOPE_AGENT);
}
__device__ __forceinline__ void fpoll(u32* f, u32 thr) {
  while (__hip_atomic_load(f, __ATOMIC_RELAXED, __HIP_MEMORY_SCOPE_AGENT) < thr)
    __builtin_amdgcn_s_sleep(1);
}

__global__ void prep_kernel(const float* __restrict__ wih0, const float* __restrict__ whh0,
                            const float* __restrict__ wih1, const float* __restrict__ whh1,
                            const float* __restrict__ wlinf,
                            u16* __restrict__ wl0a, u16* __restrict__ wl0b,
                            u16* __restrict__ wl1, u16* __restrict__ wlin) {
  int i = blockIdx.x * 256 + threadIdx.x;
  const int NA = 2048 * 512, NB = 128 * 2048, N1 = 2048 * 1024, N2 = 128 * 512;
  if (i < NA) {
    int col = i >> 9, k = i & 511;
    wl0a[i] = f2b(whh0[col * 512 + k]);
  } else if (i < NA + NB) {
    int j = i - NA, k = j >> 11, col = j & 2047;
    wl0b[j] = f2b(wih0[col * 128 + k]);
  } else if (i < NA + NB + N1) {
    int j = i - NA - NB, col = j >> 10, k = j & 1023;
    float v = (k < 512) ? wih1[col * 512 + k] : whh1[col * 512 + (k - 512)];
    wl1[j] = f2b(v);
  } else if (i < NA + NB + N1 + N2) {
    int j = i - NA - NB - N1, col = j >> 9, k = j & 511;
    wlin[j] = f2b(wlinf[col * 512 + k]);
  }
}

// 136 persistent WGs. ROUND-6 CHANGE (placement only): XCD-LOCAL TILES.
//   MI355X CP round-robins blockIdx across the 8 XCDs (bid % 8). We map
//     tile = bid & 7, slot w = bid >> 3  (8 XCDs x 17 slots = 136 WGs),
//   so ALL 17 WGs of a tile (16 compute + 1 logits) share ONE XCD's L2.
//   The per-tick h0/h1 all-to-all is then L2-local instead of crossing the
//   IF coherence point into up to 8 XCD L2s every tick (old mapping
//   XCD = w%8 dated from the weight-streaming era; weights are now fully
//   register-pinned, so spreading bought nothing per-tick).
//   Per-XCD hot set: h slices 128KB + wl0b 512KB + z 100KB << 4MB L2.
//   Predicted: FETCH_SIZE 1.66GB -> ~0.7GB (h fetch ~0), dur -15..40%.
//   wg with w<16: compute. Owns units [w*32,+32) of both layers.
//     ALL weights pinned in registers: L1 (bq1R, 256 reg -> AGPR half of the
//     unified file), L0 W_hh0 (bq0R, 128 reg). W_ih0 contribution is a
//     row-GATHER from wl0b added in the cell epilogue (one-hot MFMA removed).
//     Zero per-tick weight streaming.
//   w==16: logits WG for the tile; bumps the flag right after h1
//     staging (its only cross-WG obligation) -> off the tick critical path.
// One flag/tile/tick (round-5 protocol, WAR analysis unchanged): tick tau
// consumes h0(tau-1) [slot (tau-1)&1] and h1(tau-2) [slot tau&1]; produces
// h0(tau) [slot tau&1], h1(tau-1) [slot (tau+1)&1]. Poll F>=17*(tau+1).
__global__ __launch_bounds__(256, 1) void lstm_kernel(
    const float* __restrict__ bih0, const float* __restrict__ bhh0,
    const float* __restrict__ bih1, const float* __restrict__ bhh1,
    const float* __restrict__ blin,
    const int* __restrict__ z, const int* __restrict__ nfr,
    const u16* __restrict__ wl0a, const u16* __restrict__ wl0b,
    const u16* __restrict__ wl1, const u16* __restrict__ wlin,
    u16* __restrict__ h0buf, u16* __restrict__ h1buf,
    u32* __restrict__ bars, float* __restrict__ out) {
  extern __shared__ char smem[];
  u16* A = (u16*)smem;
  float* Gf = (float*)(smem + G_OFF_B);
  float* Pm = (float*)(smem + P_OFF_B);
  float* Ps = Pm + 256;
  float* Pt = Ps + 256;
  const int wg = blockIdx.x;
  const int w_all = wg >> 3;            // slot on the XCD: 0..16
  const bool isC = (w_all < 16);
  const int tile = wg & 7;              // XCD id; all 17 WGs of a tile co-XCD
  const int w = isC ? w_all : 16;
  const int tid = threadIdx.x, lane = tid & 63, wv = tid >> 6;
  const int l15 = lane & 15, l4 = lane >> 4;
  const int row0 = tile * RT;
  u32* F = bars + tile * 32;
  const f32x4 VZ = {0.f, 0.f, 0.f, 0.f};
  // cell-phase mapping: thread -> (row rC, 4 consecutive units u0C..+3)
  const int rC = tid >> 3, u0C = (tid & 7) * 4;
  // logits softmax mapping
  const int cuL = tid & 31, rgL = tid >> 5;

  float c0s[4] = {0, 0, 0, 0}, c1s[4] = {0, 0, 0, 0};
  float accN = 0.f, nflv = 0.f;
  float bias0c[2], bias1c[2], biasLc[2];
  bf16x8 bq0R[32];                  // L0 W_hh0: 2 cb x 16 kb = 128 reg
  bf16x8 bq1R[64];                  // L1: 2 cb x 32 kb = 256 reg (AGPR)
  bf16x8 wlR[32];                   // logits: 2 cb x 16 kb (shares slots w/ bq0R path)

  if (isC) {
#pragma unroll
    for (int cb = 0; cb < 2; ++cb) {
      int col = wv * 512 + w * 32 + cb * 16 + l15;   // gate wv, half cb
      bias0c[cb] = bih0[col] + bhh0[col];
      bias1c[cb] = bih1[col] + bhh1[col];
      const u16* b0 = wl0a + (size_t)col * 512 + l4 * 8;
#pragma unroll
      for (int kb = 0; kb < 16; ++kb) bq0R[cb * 16 + kb] = *(const bf16x8*)(b0 + kb * 32);
      const u16* b1 = wl1 + (size_t)col * 1024 + l4 * 8;
#pragma unroll
      for (int kb = 0; kb < 32; ++kb) bq1R[cb * 32 + kb] = *(const bf16x8*)(b1 + kb * 32);
    }
  } else {
#pragma unroll
    for (int cb = 0; cb < 2; ++cb) {
      int colV = wv * 32 + cb * 16 + l15;
      biasLc[cb] = blin[colV];
      const u16* bL = wlin + (size_t)colV * 512 + l4 * 8;
#pragma unroll
      for (int kb = 0; kb < 16; ++kb) wlR[cb * 16 + kb] = *(const bf16x8*)(bL + kb * 32);
    }
    if (rgL == 0) nflv = (float)nfr[row0 + cuL];
  }

  if (isC && w == 0) {
    u64* z0 = (u64*)(h0buf + HB + row0 * 512);
    u64* z1 = (u64*)(h1buf + row0 * 512);
    u64* z2 = (u64*)(h1buf + HB + row0 * 512);
    for (int k = tid; k < 2048; k += 256) { st_coh8(z0 + k, 0); st_coh8(z1 + k, 0); st_coh8(z2 + k, 0); }
  }
  __syncthreads();
  if (tid == 0) fadd(F);

  auto ldA = [&](int rb, int kb) {
    return *(const bf16x8*)(A + (rb * 16 + l15) * A_ST + kb * 32 + l4 * 8);
  };

#pragma unroll 1
  for (int tau = 0; tau <= TT + 1; ++tau) {
    if (tid == 0) fpoll(F, 17u * (u32)(tau + 1));
    __syncthreads();  // B1: tick inputs published
    const u16* h0src = h0buf + ((tau + 1) & 1) * HB + row0 * 512;
    const u64* h1s64 = (const u64*)(h1buf + (tau & 1) * HB + row0 * 512);
    const bool l0act = isC && (tau < TT);
    const bool l1act = isC && (tau >= 1 && tau <= TT);

    if (isC) {
      // ---- stage h0(tau-1): 16 batched coherent loads -> A ----
      if (tau <= TT) {
        u64 ta[8], tb[8];
        const u64* s64 = (const u64*)h0src;
#pragma unroll
        for (int c = 0; c < 8; ++c) {
          int li = c * 256 + tid;
          ta[c] = ld_coh8(s64 + li * 2); tb[c] = ld_coh8(s64 + li * 2 + 1);
        }
#pragma unroll
        for (int c = 0; c < 8; ++c) {
          int li = c * 256 + tid, row = li >> 6, cc = li & 63;
          u64* d = (u64*)(A + row * A_ST + cc * 8);
          d[0] = ta[c]; d[1] = tb[c];
        }
      }
      // issue h1(tau-2) batch1 (rows 0..15) — in flight across L0+p1 MFMA
      u64 ha[4], hb[4];
      if (l1act) {
#pragma unroll
        for (int c = 0; c < 4; ++c) {
          int li = c * 256 + tid;
          ha[c] = ld_coh8(h1s64 + li * 2); hb[c] = ld_coh8(h1s64 + li * 2 + 1);
        }
      }
      __syncthreads();  // B2: A(h0) ready

      f32x4 acc0[2][2] = {{VZ, VZ}, {VZ, VZ}};
      f32x4 acc1[2][2] = {{VZ, VZ}, {VZ, VZ}};
      if (l0act) {
#pragma unroll
        for (int kb = 0; kb < 16; ++kb) {
          bf16x8 a0 = ldA(0, kb), a1 = ldA(1, kb);
#pragma unroll
          for (int cb = 0; cb < 2; ++cb) {
            acc0[0][cb] = __builtin_amdgcn_mfma_f32_16x16x32_bf16(a0, bq0R[cb * 16 + kb], acc0[0][cb], 0, 0, 0);
            acc0[1][cb] = __builtin_amdgcn_mfma_f32_16x16x32_bf16(a1, bq0R[cb * 16 + kb], acc0[1][cb], 0, 0, 0);
          }
        }
      }
      if (l1act) {
        // L1 part 1: K 0..511 (h0(tau-1)) from A, weights in registers
#pragma unroll
        for (int kb = 0; kb < 16; ++kb) {
          bf16x8 a0 = ldA(0, kb), a1 = ldA(1, kb);
#pragma unroll
          for (int cb = 0; cb < 2; ++cb) {
            acc1[0][cb] = __builtin_amdgcn_mfma_f32_16x16x32_bf16(a0, bq1R[cb * 32 + kb], acc1[0][cb], 0, 0, 0);
            acc1[1][cb] = __builtin_amdgcn_mfma_f32_16x16x32_bf16(a1, bq1R[cb * 32 + kb], acc1[1][cb], 0, 0, 0);
          }
        }
      }
      if (l0act) {
#pragma unroll
        for (int rb = 0; rb < 2; ++rb)
#pragma unroll
          for (int cb = 0; cb < 2; ++cb)
#pragma unroll
            for (int q = 0; q < 4; ++q)
              Gf[(rb * 16 + l4 * 4 + q) * 129 + wv * 32 + cb * 16 + l15] = acc0[rb][cb][q] + bias0c[cb];
      }
      __syncthreads();  // B3: Gf(L0) ready AND all A(h0) reads done

      // issue h1 batch2 (rows 16..31) — covered by cell0 VALU
      u64 ha2[4], hb2[4];
      if (l1act) {
#pragma unroll
        for (int c = 0; c < 4; ++c) {
          int li = (c + 4) * 256 + tid;
          ha2[c] = ld_coh8(h1s64 + li * 2); hb2[c] = ld_coh8(h1s64 + li * 2 + 1);
        }
      }
      if (l0act) {
        // ---- cell0: gates + W_ih0 gather + c/h update, 8B coherent store ----
        float g4[4][4];
#pragma unroll
        for (int g = 0; g < 4; ++g)
#pragma unroll
          for (int j = 0; j < 4; ++j) g4[g][j] = Gf[rC * 129 + g * 32 + u0C + j];
        if (tau >= 1) {
          int zr = z[(row0 + rC) * TT + (tau - 1)];
          const u16* gb = wl0b + (size_t)zr * 2048 + w * 32 + u0C;
#pragma unroll
          for (int g = 0; g < 4; ++g) {
            u64 v = *(const u64*)(gb + g * 512);
#pragma unroll
            for (int j = 0; j < 4; ++j) g4[g][j] += b2f((u16)(v >> (16 * j)));
          }
        }
        u64 pk = 0;
#pragma unroll
        for (int j = 0; j < 4; ++j) {
          float cn = sigf(g4[1][j]) * c0s[j] + sigf(g4[0][j]) * tanh_f(g4[2][j]);
          float hn = sigf(g4[3][j]) * tanh_f(cn);
          c0s[j] = cn;
          pk |= ((u64)f2b(hn)) << (16 * j);
        }
        u16* h0w = h0buf + (tau & 1) * HB + row0 * 512;
        st_coh8((u64*)(h0w + rC * 512 + w * 32 + u0C), pk);
      }
      if (l1act) {
        // overwrite A with h1(tau-2)
#pragma unroll
        for (int c = 0; c < 4; ++c) {
          int li = c * 256 + tid, row = li >> 6, cc = li & 63;
          u64* d = (u64*)(A + row * A_ST + cc * 8);
          d[0] = ha[c]; d[1] = hb[c];
        }
#pragma unroll
        for (int c = 0; c < 4; ++c) {
          int li = (c + 4) * 256 + tid, row = li >> 6, cc = li & 63;
          u64* d = (u64*)(A + row * A_ST + cc * 8);
          d[0] = ha2[c]; d[1] = hb2[c];
        }
      }
      __syncthreads();  // B4: A(h1) ready AND cell0 Gf reads done

      if (l1act) {
#pragma unroll
        for (int kb = 16; kb < 32; ++kb) {
          bf16x8 a0 = ldA(0, kb - 16), a1 = ldA(1, kb - 16);
#pragma unroll
          for (int cb = 0; cb < 2; ++cb) {
            acc1[0][cb] = __builtin_amdgcn_mfma_f32_16x16x32_bf16(a0, bq1R[cb * 32 + kb], acc1[0][cb], 0, 0, 0);
            acc1[1][cb] = __builtin_amdgcn_mfma_f32_16x16x32_bf16(a1, bq1R[cb * 32 + kb], acc1[1][cb], 0, 0, 0);
          }
        }
#pragma unroll
        for (int rb = 0; rb < 2; ++rb)
#pragma unroll
          for (int cb = 0; cb < 2; ++cb)
#pragma unroll
            for (int q = 0; q < 4; ++q)
              Gf[(rb * 16 + l4 * 4 + q) * 129 + wv * 32 + cb * 16 + l15] = acc1[rb][cb][q] + bias1c[cb];
      }
      __syncthreads();  // B5: Gf(L1) ready

      if (l1act) {
        float g4[4][4];
#pragma unroll
        for (int g = 0; g < 4; ++g)
#pragma unroll
          for (int j = 0; j < 4; ++j) g4[g][j] = Gf[rC * 129 + g * 32 + u0C + j];
        u64 pk = 0;
#pragma unroll
        for (int j = 0; j < 4; ++j) {
          float cn = sigf(g4[1][j]) * c1s[j] + sigf(g4[0][j]) * tanh_f(g4[2][j]);
          float hn = sigf(g4[3][j]) * tanh_f(cn);
          c1s[j] = cn;
          pk |= ((u64)f2b(hn)) << (16 * j);
        }
        u16* h1w = h1buf + ((tau + 1) & 1) * HB + row0 * 512;
        st_coh8((u64*)(h1w + rC * 512 + w * 32 + u0C), pk);
      }
      __syncthreads();  // B6: per-wave vmcnt(0) drain => all coherent stores visible
      if (tid == 0) fadd(F);
    } else {
      // ---------------- logits WG: NLL(tau-2) ----------------
      const bool lgact = (tau >= 2);
      if (lgact) {
        u64 ta[8], tb[8];
#pragma unroll
        for (int c = 0; c < 8; ++c) {
          int li = c * 256 + tid;
          ta[c] = ld_coh8(h1s64 + li * 2); tb[c] = ld_coh8(h1s64 + li * 2 + 1);
        }
#pragma unroll
        for (int c = 0; c < 8; ++c) {
          int li = c * 256 + tid, row = li >> 6, cc = li & 63;
          u64* d = (u64*)(A + row * A_ST + cc * 8);
          d[0] = ta[c]; d[1] = tb[c];
        }
      }
      __syncthreads();  // B2: staged (loads retired)
      if (tid == 0) fadd(F);  // early release: WAR obligation met; rest is local
      if (lgact) {
        f32x4 accL[2][2] = {{VZ, VZ}, {VZ, VZ}};
#pragma unroll
        for (int kb = 0; kb < 16; ++kb) {
          bf16x8 a0 = ldA(0, kb), a1 = ldA(1, kb);
#pragma unroll
          for (int cb = 0; cb < 2; ++cb) {
            accL[0][cb] = __builtin_amdgcn_mfma_f32_16x16x32_bf16(a0, wlR[cb * 16 + kb], accL[0][cb], 0, 0, 0);
            accL[1][cb] = __builtin_amdgcn_mfma_f32_16x16x32_bf16(a1, wlR[cb * 16 + kb], accL[1][cb], 0, 0, 0);
          }
        }
#pragma unroll
        for (int rb = 0; rb < 2; ++rb)
#pragma unroll
          for (int cb = 0; cb < 2; ++cb)
#pragma unroll
            for (int q = 0; q < 4; ++q)
              Gf[(rb * 16 + l4 * 4 + q) * 129 + wv * 32 + cb * 16 + l15] = accL[rb][cb][q] + biasLc[cb];
      }
      __syncthreads();  // B3: Gf ready
      if (lgact) {
        int t2 = tau - 2;
        int r = cuL, k = rgL;            // 8 threads per row x 16 cols
        float vloc[16], mloc = -3.4e38f;
#pragma unroll
        for (int j = 0; j < 16; ++j) {
          vloc[j] = Gf[r * 129 + k * 16 + j];
          mloc = fmaxf(mloc, vloc[j]);
        }
        Pm[r * 8 + k] = mloc;
        __syncthreads();
        float mrow = Pm[r * 8];
#pragma unroll
        for (int j = 1; j < 8; ++j) mrow = fmaxf(mrow, Pm[r * 8 + j]);
        int zr = z[(row0 + r) * TT + t2];
        float sloc = 0.f, tloc = 0.f;
#pragma unroll
        for (int j = 0; j < 16; ++j) {
          sloc += __expf(vloc[j] - mrow);
          tloc += (k * 16 + j == zr) ? vloc[j] : 0.f;
        }
        Ps[r * 8 + k] = sloc; Pt[r * 8 + k] = tloc;
        __syncthreads();
        if (k == 0) {
          float s = 0.f, tv = 0.f;
#pragma unroll
          for (int j = 0; j < 8; ++j) { s += Ps[r * 8 + j]; tv += Pt[r * 8 + j]; }
          if ((float)t2 < nflv) accN += mrow + __logf(s) - tv;
        }
      } else {
        __syncthreads(); __syncthreads();
      }
    }
  }

  if (!isC && rgL == 0) out[row0 + cuL] = accN * (1.0f / TT);
}

extern "C" void kernel_launch(void* const* d_in, const int* in_sizes, int n_in,
                              void* d_out, int out_size, void* d_ws, size_t ws_size,
                              hipStream_t stream) {
  const float* wih0 = (const float*)d_in[0];
  const float* whh0 = (const float*)d_in[1];
  const float* bih0 = (const float*)d_in[2];
  const float* bhh0 = (const float*)d_in[3];
  const float* wih1 = (const float*)d_in[4];
  const float* whh1 = (const float*)d_in[5];
  const float* bih1 = (const float*)d_in[6];
  const float* bhh1 = (const float*)d_in[7];
  const float* wlinf = (const float*)d_in[8];
  const float* blin = (const float*)d_in[9];
  const int* z = (const int*)d_in[10];
  const int* nfr = (const int*)d_in[11];
  float* out = (float*)d_out;
  char* ws = (char*)d_ws;
  u16* wl0a = (u16*)(ws + WL0A_OFF);
  u16* wl0b = (u16*)(ws + WL0B_OFF);
  u16* wl1 = (u16*)(ws + WL1_OFF);
  u16* wlin = (u16*)(ws + WLIN_OFF);
  u16* h0buf = (u16*)(ws + H0_OFF);
  u16* h1buf = (u16*)(ws + H1_OFF);
  u32* bars = (u32*)(ws + BAR_OFF);

  hipMemsetAsync(ws + BAR_OFF, 0, 2048, stream);
  const int NTOT = 2048 * 512 + 128 * 2048 + 2048 * 1024 + 128 * 512;
  prep_kernel<<<dim3((NTOT + 255) / 256), dim3(256), 0, stream>>>(
      wih0, whh0, wih1, whh1, wlinf, wl0a, wl0b, wl1, wlin);
  lstm_kernel<<<dim3(NWG), dim3(256), LDS_BYTES, stream>>>(
      bih0, bhh0, bih1, bhh1, blin, z, nfr, wl0a, wl0b, wl1, wlin, h0buf, h1buf, bars, out);
}

// Round 2
// 7664.701 us; speedup vs baseline: 1.1519x; 1.1260x over previous
//
#include <hip/hip_runtime.h>

#define TT 800

typedef __attribute__((ext_vector_type(8))) short bf16x8;
typedef __attribute__((ext_vector_type(4))) float f32x4;
typedef unsigned short u16;
typedef unsigned int u32;
typedef unsigned long long u64;

constexpr int NCW = 128, NWG = 136, RT = 32;
constexpr size_t WL0A_OFF = 0;              // [2048][512] bf16 = 2,097,152 (W_hh0, K-major)
constexpr size_t WL0B_OFF = 2097152;        // [128][2048] bf16 = 524,288  (W_ih0^T row-gather)
constexpr size_t WL1_OFF  = 2621440;        // [2048][1024] bf16
constexpr size_t WLIN_OFF = 6815744;        // [128][512] bf16
constexpr size_t H0_OFF   = 6946816;        // [2][256][512] bf16
constexpr size_t H1_OFF   = 7471104;        // [2][256][512] bf16
constexpr size_t BAR_OFF  = 7995392;        // flags(1KB) + handshake (within 2KB memset)
constexpr int HB = 256 * 512;
// LDS: A = 32 rows x 520 u16 = 33280 B; Gf = 32 x 129 f32 = 16512 B @33280;
// P = 3 x 256 f32 = 3072 B @49792. Total 52864 (<64K, no opt-in needed).
constexpr int A_ST = 520;
constexpr int G_OFF_B = 33280;
constexpr int P_OFF_B = 49792;
constexpr int LDS_BYTES = 53248;

__device__ __forceinline__ u16 f2b(float x) {
  u32 u = __float_as_uint(x);
  return (u16)((u + 0x7FFFu + ((u >> 16) & 1u)) >> 16);   // RNE fp32->bf16
}
__device__ __forceinline__ float b2f(u16 v) { return __uint_as_float(((u32)v) << 16); }
__device__ __forceinline__ float sigf(float x) { return 1.f / (1.f + __expf(-x)); }
__device__ __forceinline__ float tanh_f(float x) { float e = __expf(2.f * x); return 1.f - 2.f / (e + 1.f); }

// ---- agent-scope (cross-XCD safe) ops: fallback path ----
__device__ __forceinline__ u64 ld_coh8(const u64* p) {
  return __hip_atomic_load(p, __ATOMIC_RELAXED, __HIP_MEMORY_SCOPE_AGENT);
}
__device__ __forceinline__ void st_coh8(u64* p, u64 v) {
  __hip_atomic_store(p, v, __ATOMIC_RELAXED, __HIP_MEMORY_SCOPE_AGENT);
}
__device__ __forceinline__ void fadd(u32* f) {
  __hip_atomic_fetch_add(f, 1u, __ATOMIC_RELAXED, __HIP_MEMORY_SCOPE_AGENT);
}
__device__ __forceinline__ void fpoll(u32* f, u32 thr) {
  while (__hip_atomic_load(f, __ATOMIC_RELAXED, __HIP_MEMORY_SCOPE_AGENT) < thr)
    __builtin_amdgcn_s_sleep(1);
}
// ---- XCD-local (L2-resident) ops: fast path, valid only when the whole
// tile is verified co-resident on one XCD (lok). Stores are PLAIN (line
// lands dirty in the local, writeback L2 — zero EA traffic). Loads are
// plain; freshness vs the per-CU L1 is guaranteed by an explicit
// buffer_inv (vL1 invalidate) executed by EVERY wave right after the
// tick's poll barrier, before the first h load. Flag atomics carry no sc
// bits (WORKGROUP scope) -> RMW executed at the local L2.
__device__ __forceinline__ void fadd_l(u32* f) {
  __hip_atomic_fetch_add(f, 1u, __ATOMIC_RELAXED, __HIP_MEMORY_SCOPE_WORKGROUP);
}
__device__ __forceinline__ void fpoll_l(u32* f, u32 thr) {
  while (*(volatile u32*)f < thr) {
    __builtin_amdgcn_s_sleep(1);
    asm volatile("buffer_inv" ::: "memory");   // progress even if line sits in L1
  }
}
__device__ __forceinline__ void l1inv() { asm volatile("buffer_inv" ::: "memory"); }

__global__ void prep_kernel(const float* __restrict__ wih0, const float* __restrict__ whh0,
                            const float* __restrict__ wih1, const float* __restrict__ whh1,
                            const float* __restrict__ wlinf,
                            u16* __restrict__ wl0a, u16* __restrict__ wl0b,
                            u16* __restrict__ wl1, u16* __restrict__ wlin) {
  int i = blockIdx.x * 256 + threadIdx.x;
  const int NA = 2048 * 512, NB = 128 * 2048, N1 = 2048 * 1024, N2 = 128 * 512;
  if (i < NA) {
    int col = i >> 9, k = i & 511;
    wl0a[i] = f2b(whh0[col * 512 + k]);
  } else if (i < NA + NB) {
    int j = i - NA, k = j >> 11, col = j & 2047;
    wl0b[j] = f2b(wih0[col * 128 + k]);
  } else if (i < NA + NB + N1) {
    int j = i - NA - NB, col = j >> 10, k = j & 1023;
    float v = (k < 512) ? wih1[col * 512 + k] : whh1[col * 512 + (k - 512)];
    wl1[j] = f2b(v);
  } else if (i < NA + NB + N1 + N2) {
    int j = i - NA - NB - N1, col = j >> 9, k = j & 511;
    wlin[j] = f2b(wlinf[col * 512 + k]);
  }
}

// 136 persistent WGs, XCD-local tiles (tile = bid&7, slot w = bid>>3).
// ROUND-7 CHANGE: keep the per-tick h-exchange + flag protocol INSIDE the
// tile's XCD L2. Round-6 proved co-location (FETCH 1.66GB->244MB) but dur
// barely moved: agent-scope stores write through to EA (WRITE_SIZE=433MB =
// every h store), agent loads then miss L2 (305KB/tick refetched), and the
// agent flag fadd/poll adds 2 more EA round trips -> ~5 serialized fabric
// RTs per tick = the 10.8us period. Fix: when a tile verifies (via
// s_getreg HW_REG_XCC_ID handshake, agent-scope, one-time) that all 17 of
// its WGs share one XCD, it switches to the L2-local protocol above
// (lok=true). Placement is NOT trusted for correctness: a tile that fails
// verification runs the old agent-scope path unchanged.
// Protocol (unchanged logic): tick tau consumes h0(tau-1) [slot (tau-1)&1]
// and h1(tau-2) [slot tau&1]; produces h0(tau) [slot tau&1], h1(tau-1)
// [slot (tau+1)&1]. Poll F>=17*(tau+1).
__global__ __launch_bounds__(256, 1) void lstm_kernel(
    const float* __restrict__ bih0, const float* __restrict__ bhh0,
    const float* __restrict__ bih1, const float* __restrict__ bhh1,
    const float* __restrict__ blin,
    const int* __restrict__ z, const int* __restrict__ nfr,
    const u16* __restrict__ wl0a, const u16* __restrict__ wl0b,
    const u16* __restrict__ wl1, const u16* __restrict__ wlin,
    u16* __restrict__ h0buf, u16* __restrict__ h1buf,
    u32* __restrict__ bars, float* __restrict__ out) {
  extern __shared__ char smem[];
  u16* A = (u16*)smem;
  float* Gf = (float*)(smem + G_OFF_B);
  float* Pm = (float*)(smem + P_OFF_B);
  float* Ps = Pm + 256;
  float* Pt = Ps + 256;
  const int wg = blockIdx.x;
  const int w_all = wg >> 3;            // slot on the XCD: 0..16
  const bool isC = (w_all < 16);
  const int tile = wg & 7;              // XCD id; all 17 WGs of a tile co-XCD
  const int w = isC ? w_all : 16;
  const int tid = threadIdx.x, lane = tid & 63, wv = tid >> 6;
  const int l15 = lane & 15, l4 = lane >> 4;
  const int row0 = tile * RT;
  u32* F = bars + tile * 32;
  const f32x4 VZ = {0.f, 0.f, 0.f, 0.f};
  // cell-phase mapping: thread -> (row rC, 4 consecutive units u0C..+3)
  const int rC = tid >> 3, u0C = (tid & 7) * 4;
  // logits softmax mapping
  const int cuL = tid & 31, rgL = tid >> 5;

  float c0s[4] = {0, 0, 0, 0}, c1s[4] = {0, 0, 0, 0};
  float accN = 0.f, nflv = 0.f;
  float bias0c[2], bias1c[2], biasLc[2];
  bf16x8 bq0R[32];                  // L0 W_hh0: 2 cb x 16 kb = 128 reg
  bf16x8 bq1R[64];                  // L1: 2 cb x 32 kb = 256 reg (AGPR)
  bf16x8 wlR[32];                   // logits: 2 cb x 16 kb (shares slots w/ bq0R path)

  if (isC) {
#pragma unroll
    for (int cb = 0; cb < 2; ++cb) {
      int col = wv * 512 + w * 32 + cb * 16 + l15;   // gate wv, half cb
      bias0c[cb] = bih0[col] + bhh0[col];
      bias1c[cb] = bih1[col] + bhh1[col];
      const u16* b0 = wl0a + (size_t)col * 512 + l4 * 8;
#pragma unroll
      for (int kb = 0; kb < 16; ++kb) bq0R[cb * 16 + kb] = *(const bf16x8*)(b0 + kb * 32);
      const u16* b1 = wl1 + (size_t)col * 1024 + l4 * 8;
#pragma unroll
      for (int kb = 0; kb < 32; ++kb) bq1R[cb * 32 + kb] = *(const bf16x8*)(b1 + kb * 32);
    }
  } else {
#pragma unroll
    for (int cb = 0; cb < 2; ++cb) {
      int colV = wv * 32 + cb * 16 + l15;
      biasLc[cb] = blin[colV];
      const u16* bL = wlin + (size_t)colV * 512 + l4 * 8;
#pragma unroll
      for (int kb = 0; kb < 16; ++kb) wlR[cb * 16 + kb] = *(const bf16x8*)(bL + kb * 32);
    }
    if (rgL == 0) nflv = (float)nfr[row0 + cuL];
  }

  // ---- one-time XCD co-residency handshake (agent scope, off hot path) ----
  // bars layout: [0..255] per-tile flags (tile*32); [256..263] per-tile XCD
  // masks; [272] grid init counter. All inside the 2KB memset.
  u32 xcc;
  asm volatile("s_getreg_b32 %0, hwreg(HW_REG_XCC_ID)" : "=s"(xcc));
  {
    int* hls = (int*)Pm;       // LDS broadcast slot (Pm unused until loop)
    if (tid == 0) {
      u32 bit = 1u << (xcc & 31u);
      __hip_atomic_fetch_or(bars + 256 + tile, bit, __ATOMIC_RELAXED, __HIP_MEMORY_SCOPE_AGENT);
      __hip_atomic_fetch_add(bars + 272, 1u, __ATOMIC_RELAXED, __HIP_MEMORY_SCOPE_AGENT);
      while (__hip_atomic_load(bars + 272, __ATOMIC_RELAXED, __HIP_MEMORY_SCOPE_AGENT) < (u32)NWG)
        __builtin_amdgcn_s_sleep(1);
      u32 m = __hip_atomic_load(bars + 256 + tile, __ATOMIC_RELAXED, __HIP_MEMORY_SCOPE_AGENT);
      hls[0] = (m == bit) ? 1 : 0;
    }
    __syncthreads();
    const_cast<volatile int&>(hls[0]);
  }
  const bool lok = (((volatile int*)Pm)[0] != 0);
  __syncthreads();   // everyone has read hls[0]; Pm free for reuse

  if (isC && w == 0) {
    u64* z0 = (u64*)(h0buf + HB + row0 * 512);
    u64* z1 = (u64*)(h1buf + row0 * 512);
    u64* z2 = (u64*)(h1buf + HB + row0 * 512);
    if (lok) {
      for (int k = tid; k < 2048; k += 256) { z0[k] = 0; z1[k] = 0; z2[k] = 0; }
    } else {
      for (int k = tid; k < 2048; k += 256) { st_coh8(z0 + k, 0); st_coh8(z1 + k, 0); st_coh8(z2 + k, 0); }
    }
  }
  __syncthreads();
  if (tid == 0) { if (lok) fadd_l(F); else fadd(F); }

  auto ldA = [&](int rb, int kb) {
    return *(const bf16x8*)(A + (rb * 16 + l15) * A_ST + kb * 32 + l4 * 8);
  };

#pragma unroll 1
  for (int tau = 0; tau <= TT + 1; ++tau) {
    if (tid == 0) { if (lok) fpoll_l(F, 17u * (u32)(tau + 1)); else fpoll(F, 17u * (u32)(tau + 1)); }
    __syncthreads();  // B1: tick inputs published
    if (lok) l1inv();  // every wave: drop any stale h lines from this CU's L1
    const u16* h0src = h0buf + ((tau + 1) & 1) * HB + row0 * 512;
    const u64* h1s64 = (const u64*)(h1buf + (tau & 1) * HB + row0 * 512);
    const bool l0act = isC && (tau < TT);
    const bool l1act = isC && (tau >= 1 && tau <= TT);

    if (isC) {
      // ---- stage h0(tau-1): 16 batched loads -> A ----
      if (tau <= TT) {
        u64 ta[8], tb[8];
        const u64* s64 = (const u64*)h0src;
        if (lok) {
#pragma unroll
          for (int c = 0; c < 8; ++c) {
            int li = c * 256 + tid;
            ta[c] = s64[li * 2]; tb[c] = s64[li * 2 + 1];
          }
        } else {
#pragma unroll
          for (int c = 0; c < 8; ++c) {
            int li = c * 256 + tid;
            ta[c] = ld_coh8(s64 + li * 2); tb[c] = ld_coh8(s64 + li * 2 + 1);
          }
        }
#pragma unroll
        for (int c = 0; c < 8; ++c) {
          int li = c * 256 + tid, row = li >> 6, cc = li & 63;
          u64* d = (u64*)(A + row * A_ST + cc * 8);
          d[0] = ta[c]; d[1] = tb[c];
        }
      }
      // issue h1(tau-2) batch1 (rows 0..15) — in flight across L0+p1 MFMA
      u64 ha[4], hb[4];
      if (l1act) {
        if (lok) {
#pragma unroll
          for (int c = 0; c < 4; ++c) {
            int li = c * 256 + tid;
            ha[c] = h1s64[li * 2]; hb[c] = h1s64[li * 2 + 1];
          }
        } else {
#pragma unroll
          for (int c = 0; c < 4; ++c) {
            int li = c * 256 + tid;
            ha[c] = ld_coh8(h1s64 + li * 2); hb[c] = ld_coh8(h1s64 + li * 2 + 1);
          }
        }
      }
      __syncthreads();  // B2: A(h0) ready

      f32x4 acc0[2][2] = {{VZ, VZ}, {VZ, VZ}};
      f32x4 acc1[2][2] = {{VZ, VZ}, {VZ, VZ}};
      if (l0act) {
#pragma unroll
        for (int kb = 0; kb < 16; ++kb) {
          bf16x8 a0 = ldA(0, kb), a1 = ldA(1, kb);
#pragma unroll
          for (int cb = 0; cb < 2; ++cb) {
            acc0[0][cb] = __builtin_amdgcn_mfma_f32_16x16x32_bf16(a0, bq0R[cb * 16 + kb], acc0[0][cb], 0, 0, 0);
            acc0[1][cb] = __builtin_amdgcn_mfma_f32_16x16x32_bf16(a1, bq0R[cb * 16 + kb], acc0[1][cb], 0, 0, 0);
          }
        }
      }
      if (l1act) {
        // L1 part 1: K 0..511 (h0(tau-1)) from A, weights in registers
#pragma unroll
        for (int kb = 0; kb < 16; ++kb) {
          bf16x8 a0 = ldA(0, kb), a1 = ldA(1, kb);
#pragma unroll
          for (int cb = 0; cb < 2; ++cb) {
            acc1[0][cb] = __builtin_amdgcn_mfma_f32_16x16x32_bf16(a0, bq1R[cb * 32 + kb], acc1[0][cb], 0, 0, 0);
            acc1[1][cb] = __builtin_amdgcn_mfma_f32_16x16x32_bf16(a1, bq1R[cb * 32 + kb], acc1[1][cb], 0, 0, 0);
          }
        }
      }
      if (l0act) {
#pragma unroll
        for (int rb = 0; rb < 2; ++rb)
#pragma unroll
          for (int cb = 0; cb < 2; ++cb)
#pragma unroll
            for (int q = 0; q < 4; ++q)
              Gf[(rb * 16 + l4 * 4 + q) * 129 + wv * 32 + cb * 16 + l15] = acc0[rb][cb][q] + bias0c[cb];
      }
      __syncthreads();  // B3: Gf(L0) ready AND all A(h0) reads done

      // issue h1 batch2 (rows 16..31) — covered by cell0 VALU
      u64 ha2[4], hb2[4];
      if (l1act) {
        if (lok) {
#pragma unroll
          for (int c = 0; c < 4; ++c) {
            int li = (c + 4) * 256 + tid;
            ha2[c] = h1s64[li * 2]; hb2[c] = h1s64[li * 2 + 1];
          }
        } else {
#pragma unroll
          for (int c = 0; c < 4; ++c) {
            int li = (c + 4) * 256 + tid;
            ha2[c] = ld_coh8(h1s64 + li * 2); hb2[c] = ld_coh8(h1s64 + li * 2 + 1);
          }
        }
      }
      if (l0act) {
        // ---- cell0: gates + W_ih0 gather + c/h update, 8B store ----
        float g4[4][4];
#pragma unroll
        for (int g = 0; g < 4; ++g)
#pragma unroll
          for (int j = 0; j < 4; ++j) g4[g][j] = Gf[rC * 129 + g * 32 + u0C + j];
        if (tau >= 1) {
          int zr = z[(row0 + rC) * TT + (tau - 1)];
          const u16* gb = wl0b + (size_t)zr * 2048 + w * 32 + u0C;
#pragma unroll
          for (int g = 0; g < 4; ++g) {
            u64 v = *(const u64*)(gb + g * 512);
#pragma unroll
            for (int j = 0; j < 4; ++j) g4[g][j] += b2f((u16)(v >> (16 * j)));
          }
        }
        u64 pk = 0;
#pragma unroll
        for (int j = 0; j < 4; ++j) {
          float cn = sigf(g4[1][j]) * c0s[j] + sigf(g4[0][j]) * tanh_f(g4[2][j]);
          float hn = sigf(g4[3][j]) * tanh_f(cn);
          c0s[j] = cn;
          pk |= ((u64)f2b(hn)) << (16 * j);
        }
        u16* h0w = h0buf + (tau & 1) * HB + row0 * 512;
        u64* dst = (u64*)(h0w + rC * 512 + w * 32 + u0C);
        if (lok) *dst = pk; else st_coh8(dst, pk);
      }
      if (l1act) {
        // overwrite A with h1(tau-2)
#pragma unroll
        for (int c = 0; c < 4; ++c) {
          int li = c * 256 + tid, row = li >> 6, cc = li & 63;
          u64* d = (u64*)(A + row * A_ST + cc * 8);
          d[0] = ha[c]; d[1] = hb[c];
        }
#pragma unroll
        for (int c = 0; c < 4; ++c) {
          int li = (c + 4) * 256 + tid, row = li >> 6, cc = li & 63;
          u64* d = (u64*)(A + row * A_ST + cc * 8);
          d[0] = ha2[c]; d[1] = hb2[c];
        }
      }
      __syncthreads();  // B4: A(h1) ready AND cell0 Gf reads done

      if (l1act) {
#pragma unroll
        for (int kb = 16; kb < 32; ++kb) {
          bf16x8 a0 = ldA(0, kb - 16), a1 = ldA(1, kb - 16);
#pragma unroll
          for (int cb = 0; cb < 2; ++cb) {
            acc1[0][cb] = __builtin_amdgcn_mfma_f32_16x16x32_bf16(a0, bq1R[cb * 32 + kb], acc1[0][cb], 0, 0, 0);
            acc1[1][cb] = __builtin_amdgcn_mfma_f32_16x16x32_bf16(a1, bq1R[cb * 32 + kb], acc1[1][cb], 0, 0, 0);
          }
        }
#pragma unroll
        for (int rb = 0; rb < 2; ++rb)
#pragma unroll
          for (int cb = 0; cb < 2; ++cb)
#pragma unroll
            for (int q = 0; q < 4; ++q)
              Gf[(rb * 16 + l4 * 4 + q) * 129 + wv * 32 + cb * 16 + l15] = acc1[rb][cb][q] + bias1c[cb];
      }
      __syncthreads();  // B5: Gf(L1) ready

      if (l1act) {
        float g4[4][4];
#pragma unroll
        for (int g = 0; g < 4; ++g)
#pragma unroll
          for (int j = 0; j < 4; ++j) g4[g][j] = Gf[rC * 129 + g * 32 + u0C + j];
        u64 pk = 0;
#pragma unroll
        for (int j = 0; j < 4; ++j) {
          float cn = sigf(g4[1][j]) * c1s[j] + sigf(g4[0][j]) * tanh_f(g4[2][j]);
          float hn = sigf(g4[3][j]) * tanh_f(cn);
          c1s[j] = cn;
          pk |= ((u64)f2b(hn)) << (16 * j);
        }
        u16* h1w = h1buf + ((tau + 1) & 1) * HB + row0 * 512;
        u64* dst = (u64*)(h1w + rC * 512 + w * 32 + u0C);
        if (lok) *dst = pk; else st_coh8(dst, pk);
      }
      __syncthreads();  // B6: per-wave vmcnt(0) drain => stores in L2 (lok) / visible (agent)
      if (tid == 0) { if (lok) fadd_l(F); else fadd(F); }
    } else {
      // ---------------- logits WG: NLL(tau-2) ----------------
      const bool lgact = (tau >= 2);
      if (lgact) {
        u64 ta[8], tb[8];
        if (lok) {
#pragma unroll
          for (int c = 0; c < 8; ++c) {
            int li = c * 256 + tid;
            ta[c] = h1s64[li * 2]; tb[c] = h1s64[li * 2 + 1];
          }
        } else {
#pragma unroll
          for (int c = 0; c < 8; ++c) {
            int li = c * 256 + tid;
            ta[c] = ld_coh8(h1s64 + li * 2); tb[c] = ld_coh8(h1s64 + li * 2 + 1);
          }
        }
#pragma unroll
        for (int c = 0; c < 8; ++c) {
          int li = c * 256 + tid, row = li >> 6, cc = li & 63;
          u64* d = (u64*)(A + row * A_ST + cc * 8);
          d[0] = ta[c]; d[1] = tb[c];
        }
      }
      __syncthreads();  // B2: staged (loads retired)
      if (tid == 0) { if (lok) fadd_l(F); else fadd(F); }  // early release
      if (lgact) {
        f32x4 accL[2][2] = {{VZ, VZ}, {VZ, VZ}};
#pragma unroll
        for (int kb = 0; kb < 16; ++kb) {
          bf16x8 a0 = ldA(0, kb), a1 = ldA(1, kb);
#pragma unroll
          for (int cb = 0; cb < 2; ++cb) {
            accL[0][cb] = __builtin_amdgcn_mfma_f32_16x16x32_bf16(a0, wlR[cb * 16 + kb], accL[0][cb], 0, 0, 0);
            accL[1][cb] = __builtin_amdgcn_mfma_f32_16x16x32_bf16(a1, wlR[cb * 16 + kb], accL[1][cb], 0, 0, 0);
          }
        }
#pragma unroll
        for (int rb = 0; rb < 2; ++rb)
#pragma unroll
          for (int cb = 0; cb < 2; ++cb)
#pragma unroll
            for (int q = 0; q < 4; ++q)
              Gf[(rb * 16 + l4 * 4 + q) * 129 + wv * 32 + cb * 16 + l15] = accL[rb][cb][q] + biasLc[cb];
      }
      __syncthreads();  // B3: Gf ready
      if (lgact) {
        int t2 = tau - 2;
        int r = cuL, k = rgL;            // 8 threads per row x 16 cols
        float vloc[16], mloc = -3.4e38f;
#pragma unroll
        for (int j = 0; j < 16; ++j) {
          vloc[j] = Gf[r * 129 + k * 16 + j];
          mloc = fmaxf(mloc, vloc[j]);
        }
        Pm[r * 8 + k] = mloc;
        __syncthreads();
        float mrow = Pm[r * 8];
#pragma unroll
        for (int j = 1; j < 8; ++j) mrow = fmaxf(mrow, Pm[r * 8 + j]);
        int zr = z[(row0 + r) * TT + t2];
        float sloc = 0.f, tloc = 0.f;
#pragma unroll
        for (int j = 0; j < 16; ++j) {
          sloc += __expf(vloc[j] - mrow);
          tloc += (k * 16 + j == zr) ? vloc[j] : 0.f;
        }
        Ps[r * 8 + k] = sloc; Pt[r * 8 + k] = tloc;
        __syncthreads();
        if (k == 0) {
          float s = 0.f, tv = 0.f;
#pragma unroll
          for (int j = 0; j < 8; ++j) { s += Ps[r * 8 + j]; tv += Pt[r * 8 + j]; }
          if ((float)t2 < nflv) accN += mrow + __logf(s) - tv;
        }
      } else {
        __syncthreads(); __syncthreads();
      }
    }
  }

  if (!isC && rgL == 0) out[row0 + cuL] = accN * (1.0f / TT);
}

extern "C" void kernel_launch(void* const* d_in, const int* in_sizes, int n_in,
                              void* d_out, int out_size, void* d_ws, size_t ws_size,
                              hipStream_t stream) {
  const float* wih0 = (const float*)d_in[0];
  const float* whh0 = (const float*)d_in[1];
  const float* bih0 = (const float*)d_in[2];
  const float* bhh0 = (const float*)d_in[3];
  const float* wih1 = (const float*)d_in[4];
  const float* whh1 = (const float*)d_in[5];
  const float* bih1 = (const float*)d_in[6];
  const float* bhh1 = (const float*)d_in[7];
  const float* wlinf = (const float*)d_in[8];
  const float* blin = (const float*)d_in[9];
  const int* z = (const int*)d_in[10];
  const int* nfr = (const int*)d_in[11];
  float* out = (float*)d_out;
  char* ws = (char*)d_ws;
  u16* wl0a = (u16*)(ws + WL0A_OFF);
  u16* wl0b = (u16*)(ws + WL0B_OFF);
  u16* wl1 = (u16*)(ws + WL1_OFF);
  u16* wlin = (u16*)(ws + WLIN_OFF);
  u16* h0buf = (u16*)(ws + H0_OFF);
  u16* h1buf = (u16*)(ws + H1_OFF);
  u32* bars = (u32*)(ws + BAR_OFF);

  hipMemsetAsync(ws + BAR_OFF, 0, 2048, stream);
  const int NTOT = 2048 * 512 + 128 * 2048 + 2048 * 1024 + 128 * 512;
  prep_kernel<<<dim3((NTOT + 255) / 256), dim3(256), 0, stream>>>(
      wih0, whh0, wih1, whh1, wlinf, wl0a, wl0b, wl1, wlin);
  lstm_kernel<<<dim3(NWG), dim3(256), LDS_BYTES, stream>>>(
      bih0, bhh0, bih1, bhh1, blin, z, nfr, wl0a, wl0b, wl1, wlin, h0buf, h1buf, bars, out);
}